// Round 3
// baseline (95.981 us; speedup 1.0000x reference)
//
#include <hip/hip_runtime.h>
#include <math.h>

#define Bn   2
#define En   2048
#define N1n  96
#define Kn   32
#define CINn 64
#define CBn  32
#define On   64
#define Gn   4
#define Fn   160   // 2*CIN + CB
#define NEG  0.01f
#define NW   8          // waves per block
#define NT   (NW * 64)  // 512 threads
#define EB   2          // edges batched per wave per Weff sweep
#define SUBn 8          // sub-blocks per (b,k2) bucket
#define LCAP 160        // per-k2 edge list capacity (mean 64, binomial max ~100)

// d_ws layout (poisoned each iteration; fully rewritten by prep_kernel):
//   int   tick[64]                  @ int offset 0      (zeroed by prep)
//   int   cnt [32]                  @ int offset 64
//   int   list[32][LCAP]            @ int offset 256
//   float weff[32][Fn][On]          @ float offset 8192   (1.31 MB)
//   float part[64][SUBn][On]        @ float offset 8192 + 32*Fn*On
#define WS_TICK 0
#define WS_CNT  64
#define WS_LIST 256
#define WS_WEFF 8192
#define WS_PART (8192 + 32 * Fn * On)

// ---------------------------------------------------------------------------
// R5: hoist all bucket-invariant work out of the hot kernel.
//  * prep_kernel computes the 32 Weff matrices ONCE (they depend only on k2,
//    not b; R4 recomputed each 16x = 80 MB of L2 traffic ~2.3us) and builds
//    one edge list per k2 (R4 re-scanned idx2 per block). Also zeroes the
//    split-K tickets.
//  * fused_kernel: Weff staging becomes a 40KB straight copy; wgs/perms
//    chain gone; elist is a read-only chunk of the prebuilt list (position
//    chunking is safe now - single writer, read-only after prep).
//  * reduce_kernel dispatch removed: canonical split-K tail. Each sub-block
//    stores its partial, __threadfence() (agent-scope release: L2 writeback,
//    required for cross-XCD visibility), takes a ticket; the last sub-block
//    of a bucket fences (acquire: cache inv) and sums the 8 partials in a
//    FIXED order -> deterministic within a run.
// Per-edge math byte-identical to the harness-verified R4 kernel.
// ---------------------------------------------------------------------------
__global__ void __launch_bounds__(NT)
prep_kernel(const float* __restrict__ W_eq, const int* __restrict__ perms1,
            const int* __restrict__ perms2, const int* __restrict__ idx2,
            float* __restrict__ wsf) {
    int* wsi = (int*)wsf;
    const int t    = threadIdx.x;
    const int role = blockIdx.x;

    if (role < 64) {
        // Weff for k2 = role>>1, half = role&1 (split for latency, 64 CUs busy)
        const int k2 = role >> 1;
        __shared__ float wgs[Gn];
        // wgs[g] = [perms1[g,j]==k2] at the unique j with perms2[g,j]==k2
        if (t < Gn) wgs[t] = 0.f;
        __builtin_amdgcn_wave_barrier();
        if (t < 64) {
            const int pa2 = perms2[t],      pa1 = perms1[t];
            const int pb2 = perms2[t + 64], pb1 = perms1[t + 64];
            if (pa2 == k2 && pa1 == k2) wgs[t >> 5] = 1.f;
            if (pb2 == k2 && pb1 == k2) wgs[(t + 64) >> 5] = 1.f;
        }
        __syncthreads();
        const float w0 = wgs[0], w1 = wgs[1], w2 = wgs[2], w3 = wgs[3];
        const float4* W4 = (const float4*)W_eq;
        float4* Wd = (float4*)(wsf + WS_WEFF + k2 * (Fn * On));
        const int n4 = Fn * On / 4;            // 2560
        const int i0 = (role & 1) * (n4 / 2);  // half-split
        for (int i = i0 + t; i < i0 + n4 / 2; i += NT) {
            float4 a0 = W4[i], a1 = W4[n4 + i], a2 = W4[2 * n4 + i], a3 = W4[3 * n4 + i];
            float4 r;
            r.x = 0.25f * (w0 * a0.x + w1 * a1.x + w2 * a2.x + w3 * a3.x);
            r.y = 0.25f * (w0 * a0.y + w1 * a1.y + w2 * a2.y + w3 * a3.y);
            r.z = 0.25f * (w0 * a0.z + w1 * a1.z + w2 * a2.z + w3 * a3.z);
            r.w = 0.25f * (w0 * a0.w + w1 * a1.w + w2 * a2.w + w3 * a3.w);
            Wd[i] = r;
        }
    } else {
        // edge list for k2 = role-64 (idx2 is b-independent)
        const int k2 = role - 64;
        __shared__ int cntS;
        if (t == 0) cntS = 0;
        if (role == 64 && t < 64) wsi[WS_TICK + t] = 0;   // zero split-K tickets
        __syncthreads();
        for (int e = t; e < En; e += NT)
            if (idx2[e] == k2) {
                int p = atomicAdd(&cntS, 1);
                if (p < LCAP) wsi[WS_LIST + k2 * LCAP + p] = e;
            }
        __syncthreads();
        if (t == 0) wsi[WS_CNT + k2] = cntS < LCAP ? cntS : LCAP;
    }
}

// ---------------------------------------------------------------------------
__global__ void __launch_bounds__(NT, 4)
fused_kernel(const float* __restrict__ sites1, const float* __restrict__ sites2,
             const float* __restrict__ bonds,  const float* __restrict__ b_eq,
             const float* __restrict__ W_att,  const float* __restrict__ b_att,
             const int* __restrict__ idx1,     float* __restrict__ wsf,
             float* __restrict__ out) {
    __shared__ float Weff[Fn][On];       // 40960 B
    __shared__ float vs[NW][EB][96];     //  6144 B
    __shared__ float red[NW][On];        //  2048 B
    __shared__ float s2[CINn];           //   256 B
    __shared__ int   el[64];             //   256 B
    __shared__ int   s_last;

    int* wsi = (int*)wsf;
    const int t      = threadIdx.x;
    const int bucket = blockIdx.x >> 3;  // (b,k2)
    const int sub    = blockIdx.x & (SUBn - 1);
    const int b      = bucket >> 5;      // Kn = 32
    const int k2     = bucket & (Kn - 1);

    // my chunk of the prebuilt per-k2 edge list (uniform across threads)
    const int c  = wsi[WS_CNT + k2];
    const int ch = (c + SUBn - 1) >> 3;
    const int lo = sub * ch;
    int n = c - lo; if (n > ch) n = ch; if (n < 0) n = 0;
    if (t < n) el[t] = wsi[WS_LIST + k2 * LCAP + lo + t];

    // stage Weff[k2] (straight copy, 5 float4/thread) + s2 row
    {
        const float4* Ws4 = (const float4*)(wsf + WS_WEFF + k2 * (Fn * On));
        float4* Wd = (float4*)&Weff[0][0];
#pragma unroll
        for (int i = t; i < Fn * On / 4; i += NT) Wd[i] = Ws4[i];
    }
    if (t < CINn) s2[t] = sites2[(b * Kn + k2) * CINn + t];
    __syncthreads();

    const int w    = t >> 6;
    const int lane = t & 63;
    const int og   = lane & 15;          // output quad: o = 4*og .. 4*og+3
    const int fg   = lane >> 4;          // f stripe: f ≡ fg (mod 4)

    const float4 be4 = ((const float4*)b_eq)[og];
    const float4 wa  = ((const float4*)W_att)[og];
    const float  ba  = b_att[0];

    // shared sites2 partial: p2 = sum_{f in [64,128)} s2[f-64] * Weff[f][4og..]
    float4 p2 = make_float4(0.f, 0.f, 0.f, 0.f);
#pragma unroll
    for (int fi = 0; fi < 16; ++fi) {
        const int f  = 64 + 4 * fi + fg;
        const float  vf = s2[4 * fi + fg];
        const float4 wv = *(const float4*)&Weff[f][og * 4];
        p2.x += vf * wv.x; p2.y += vf * wv.y;
        p2.z += vf * wv.z; p2.w += vf * wv.w;
    }

    float4 oacc = make_float4(0.f, 0.f, 0.f, 0.f);

    for (int base = w * EB; base < n; base += NW * EB) {
        const int nb = (n - base < EB) ? (n - base) : EB;

        // stage this batch's varying v entries: [sites1 row | bonds row]
        __builtin_amdgcn_wave_barrier();
#pragma unroll
        for (int j = 0; j < EB; ++j) {
            const int jj = j < nb ? j : nb - 1;    // clamp: pads reuse a valid edge
            const int e  = el[base + jj];
            const int i1 = idx1[e];
            vs[w][j][lane] = sites1[((b * N1n + i1) << 6) + lane];
            if (lane < CBn) vs[w][j][CINn + lane] = bonds[(b * En + e) * CBn + lane];
        }
        __builtin_amdgcn_wave_barrier();

        float4 acc[EB];
#pragma unroll
        for (int j = 0; j < EB; ++j) acc[j] = p2;

        // matvec over the 96 varying f's; each Weff b128 feeds all EB edges
#pragma unroll
        for (int fi = 0; fi < 24; ++fi) {
            const int vsidx = 4 * fi + fg;
            const int f     = vsidx < CINn ? vsidx : vsidx + CINn;  // skip s2 band
            const float4 wv = *(const float4*)&Weff[f][og * 4];
#pragma unroll
            for (int j = 0; j < EB; ++j) {
                const float vf = vs[w][j][vsidx];
                acc[j].x += vf * wv.x; acc[j].y += vf * wv.y;
                acc[j].z += vf * wv.z; acc[j].w += vf * wv.w;
            }
        }
        __builtin_amdgcn_wave_barrier();

        // per-edge epilogue
#pragma unroll
        for (int j = 0; j < EB; ++j) {
            float4 a = acc[j];
#pragma unroll
            for (int m = 16; m <= 32; m <<= 1) {     // reduce the 4 f stripes
                a.x += __shfl_xor(a.x, m);
                a.y += __shfl_xor(a.y, m);
                a.z += __shfl_xor(a.z, m);
                a.w += __shfl_xor(a.w, m);
            }
            float4 lat;
            lat.x = a.x + be4.x; lat.x = lat.x > 0.f ? lat.x : NEG * lat.x;
            lat.y = a.y + be4.y; lat.y = lat.y > 0.f ? lat.y : NEG * lat.y;
            lat.z = a.z + be4.z; lat.z = lat.z > 0.f ? lat.z : NEG * lat.z;
            lat.w = a.w + be4.w; lat.w = lat.w > 0.f ? lat.w : NEG * lat.w;

            float part = lat.x * wa.x + lat.y * wa.y + lat.z * wa.z + lat.w * wa.w;
#pragma unroll
            for (int m = 1; m <= 8; m <<= 1) part += __shfl_xor(part, m);

            float att = 1.f / (1.f + expf(-(part + ba)));
            att *= (j < nb) ? 1.f : 0.f;             // mask clamp-padded edges
            oacc.x += att * lat.x;
            oacc.y += att * lat.y;
            oacc.z += att * lat.z;
            oacc.w += att * lat.w;
        }
    }

    if (fg == 0) *(float4*)&red[w][og * 4] = oacc;
    __syncthreads();

    // store this sub-block's 64-float partial
    if (t < On) {
        float s = 0.f;
#pragma unroll
        for (int q = 0; q < NW; ++q) s += red[q][t];
        wsf[WS_PART + ((size_t)bucket * SUBn + sub) * On + t] = s;
    }
    __syncthreads();   // drains the partial stores (vmcnt(0) before barrier)

    // split-K tail: last sub-block of the bucket reduces deterministically
    if (t == 0) {
        __threadfence();                         // release: L2 writeback
        int old = atomicAdd(&wsi[WS_TICK + bucket], 1);
        int last = (old == SUBn - 1);
        if (last) __threadfence();               // acquire: cache invalidate
        s_last = last;
    }
    __syncthreads();
    if (s_last && t < On) {
        const float* p = wsf + WS_PART + (size_t)bucket * SUBn * On + t;
        float s01 = p[0]      + p[On];
        float s23 = p[2 * On] + p[3 * On];
        float s45 = p[4 * On] + p[5 * On];
        float s67 = p[6 * On] + p[7 * On];
        out[bucket * On + t] = (s01 + s23) + (s45 + s67);
    }
}

// ---------------------------------------------------------------------------
extern "C" void kernel_launch(void* const* d_in, const int* in_sizes, int n_in,
                              void* d_out, int out_size, void* d_ws, size_t ws_size,
                              hipStream_t stream) {
    const float* sites1 = (const float*)d_in[0];
    const float* sites2 = (const float*)d_in[1];
    const float* bonds  = (const float*)d_in[2];
    const float* W_eq   = (const float*)d_in[3];
    const float* b_eq   = (const float*)d_in[4];
    const float* W_att  = (const float*)d_in[5];
    const float* b_att  = (const float*)d_in[6];
    /* d_in[7] = idx2_oh (unused — reduced algebraically) */
    const int*   idx1   = (const int*)d_in[8];
    const int*   idx2   = (const int*)d_in[9];
    const int*   perms1 = (const int*)d_in[10];
    const int*   perms2 = (const int*)d_in[11];
    float* out = (float*)d_out;
    float* wsf = (float*)d_ws;

    prep_kernel<<<96, NT, 0, stream>>>(W_eq, perms1, perms2, idx2, wsf);
    fused_kernel<<<Bn * Kn * SUBn, NT, 0, stream>>>(
        sites1, sites2, bonds, b_eq, W_att, b_att, idx1, wsf, out);
}

// Round 4
// 84.205 us; speedup vs baseline: 1.1399x; 1.1399x over previous
//
#include <hip/hip_runtime.h>
#include <math.h>

#define Bn   2
#define En   2048
#define N1n  96
#define Kn   32
#define CINn 64
#define CBn  32
#define On   64
#define Gn   4
#define Fn   160   // 2*CIN + CB
#define NEG  0.01f
#define NW   8          // waves per block
#define NT   (NW * 64)  // 512 threads
#define EB   2          // edges batched per wave per Weff sweep
#define SUBn 8          // sub-blocks per (b,k2) bucket
#define ELCAP 128       // elist capacity per sub-block (mean 4, huge margin)

// ---------------------------------------------------------------------------
// R6: REVERT to the harness-verified R4 structure (84.6us). R5's hoisting
// (prep kernel + split-K fence tail) regressed +11.4us: it traded cheap,
// fully-overlapped redundant staging for a serialized dependent dispatch,
// cross-XCD L2 misses on the precomputed Weff, and 512 device-scope fences.
// Lesson recorded: the fused kernel's total budget is ~5-7us of an ~80us
// harness floor (2x 40us workspace re-poison fills at 84% HBM peak).
// Only change vs R4: the idx2 scan values and the s2 row are prefetched
// into flight BEFORE the first __syncthreads(), so their latency overlaps
// the wgs perms round-trip instead of following it (same instruction
// stream, earlier issue; no structural change).
// ---------------------------------------------------------------------------
__global__ void __launch_bounds__(NT, 4)
fused_kernel(const float* __restrict__ sites1, const float* __restrict__ sites2,
             const float* __restrict__ bonds,  const float* __restrict__ W_eq,
             const float* __restrict__ b_eq,   const float* __restrict__ W_att,
             const float* __restrict__ b_att,  const int* __restrict__ idx1,
             const int* __restrict__ idx2,     const int* __restrict__ perms1,
             const int* __restrict__ perms2,   float* __restrict__ ws) {
    __shared__ float Weff[Fn][On];       // 40960 B
    __shared__ float vs[NW][EB][96];     //  6144 B
    __shared__ float red[NW][On];        //  2048 B
    __shared__ float s2[CINn];           //   256 B
    __shared__ float wgs[Gn];
    __shared__ int   elist[ELCAP];       //   512 B
    __shared__ int   ecount;

    const int t      = threadIdx.x;
    const int bucket = blockIdx.x >> 3;  // (b,k2)
    const int sub    = blockIdx.x & (SUBn - 1);
    const int b      = bucket >> 5;      // Kn = 32
    const int k2     = bucket & (Kn - 1);

    // --- prefetch: issue idx2 scan loads + s2 row load NOW, so their
    // latency overlaps the wgs perms round-trip below.
    const int q0 = idx2[t];
    const int q1 = idx2[t + NT];
    const int q2 = idx2[t + 2 * NT];
    const int q3 = idx2[t + 3 * NT];
    if (t < CINn) s2[t] = sites2[(b * Kn + k2) * CINn + t];

    // wgs[g] = [perms1[g,j]==k2] at the unique j where perms2[g,j]==k2.
    // All done by wave 0 (wave-synchronous LDS ordering).
    if (t < Gn) wgs[t] = 0.f;
    __builtin_amdgcn_wave_barrier();
    if (t < 64) {
        const int pa2 = perms2[t],      pa1 = perms1[t];
        const int pb2 = perms2[t + 64], pb1 = perms1[t + 64];
        if (pa2 == k2 && pa1 == k2) wgs[t >> 5] = 1.f;
        if (pb2 == k2 && pb1 == k2) wgs[(t + 64) >> 5] = 1.f;
    }
    if (t == 64) ecount = 0;             // wave 1, independent of wgs
    __syncthreads();

    // build this sub-block's edge list from the prefetched idx2 values
    {
        const int e0 = t, e1 = t + NT, e2 = t + 2 * NT, e3 = t + 3 * NT;
        if (q0 == k2 && (e0 & (SUBn - 1)) == sub) elist[atomicAdd(&ecount, 1)] = e0;
        if (q1 == k2 && (e1 & (SUBn - 1)) == sub) elist[atomicAdd(&ecount, 1)] = e1;
        if (q2 == k2 && (e2 & (SUBn - 1)) == sub) elist[atomicAdd(&ecount, 1)] = e2;
        if (q3 == k2 && (e3 & (SUBn - 1)) == sub) elist[atomicAdd(&ecount, 1)] = e3;
    }

    // stage Weff[k2] into LDS (float4-wise, coalesced; W_eq is L2-hot)
    {
        const float w0 = wgs[0], w1 = wgs[1], w2 = wgs[2], w3 = wgs[3];
        const float4* W4 = (const float4*)W_eq;
        float4* Wd = (float4*)&Weff[0][0];
        const int n4 = Fn * On / 4;      // 2560 float4 per group
#pragma unroll
        for (int i = t; i < n4; i += NT) {
            float4 a0 = W4[i], a1 = W4[n4 + i], a2 = W4[2 * n4 + i], a3 = W4[3 * n4 + i];
            float4 r;
            r.x = 0.25f * (w0 * a0.x + w1 * a1.x + w2 * a2.x + w3 * a3.x);
            r.y = 0.25f * (w0 * a0.y + w1 * a1.y + w2 * a2.y + w3 * a3.y);
            r.z = 0.25f * (w0 * a0.z + w1 * a1.z + w2 * a2.z + w3 * a3.z);
            r.w = 0.25f * (w0 * a0.w + w1 * a1.w + w2 * a2.w + w3 * a3.w);
            Wd[i] = r;
        }
    }
    __syncthreads();

    const int w    = t >> 6;
    const int lane = t & 63;
    const int og   = lane & 15;          // output quad: o = 4*og .. 4*og+3
    const int fg   = lane >> 4;          // f stripe: f ≡ fg (mod 4)
    const int ec   = ecount;

    const float4 be4 = ((const float4*)b_eq)[og];
    const float4 wa  = ((const float4*)W_att)[og];
    const float  ba  = b_att[0];

    // shared sites2 partial: p2 = sum_{f in [64,128)} s2[f-64] * Weff[f][4og..]
    float4 p2 = make_float4(0.f, 0.f, 0.f, 0.f);
#pragma unroll
    for (int fi = 0; fi < 16; ++fi) {
        const int f  = 64 + 4 * fi + fg;
        const float  vf = s2[4 * fi + fg];
        const float4 wv = *(const float4*)&Weff[f][og * 4];
        p2.x += vf * wv.x; p2.y += vf * wv.y;
        p2.z += vf * wv.z; p2.w += vf * wv.w;
    }

    float4 oacc = make_float4(0.f, 0.f, 0.f, 0.f);

    for (int base = w * EB; base < ec; base += NW * EB) {
        const int nb = (ec - base < EB) ? (ec - base) : EB;

        // stage this batch's varying v entries: [sites1 row | bonds row]
        __builtin_amdgcn_wave_barrier();
#pragma unroll
        for (int j = 0; j < EB; ++j) {
            const int jj = j < nb ? j : nb - 1;    // clamp: pads reuse a valid edge
            const int e  = elist[base + jj];
            const int i1 = idx1[e];
            vs[w][j][lane] = sites1[((b * N1n + i1) << 6) + lane];
            if (lane < CBn) vs[w][j][CINn + lane] = bonds[(b * En + e) * CBn + lane];
        }
        __builtin_amdgcn_wave_barrier();

        float4 acc[EB];
#pragma unroll
        for (int j = 0; j < EB; ++j) acc[j] = p2;

        // matvec over the 96 varying f's; each Weff b128 feeds all EB edges
#pragma unroll
        for (int fi = 0; fi < 24; ++fi) {
            const int vsidx = 4 * fi + fg;
            const int f     = vsidx < CINn ? vsidx : vsidx + CINn;  // skip s2 band
            const float4 wv = *(const float4*)&Weff[f][og * 4];
#pragma unroll
            for (int j = 0; j < EB; ++j) {
                const float vf = vs[w][j][vsidx];
                acc[j].x += vf * wv.x; acc[j].y += vf * wv.y;
                acc[j].z += vf * wv.z; acc[j].w += vf * wv.w;
            }
        }
        __builtin_amdgcn_wave_barrier();

        // per-edge epilogue
#pragma unroll
        for (int j = 0; j < EB; ++j) {
            float4 a = acc[j];
#pragma unroll
            for (int m = 16; m <= 32; m <<= 1) {     // reduce the 4 f stripes
                a.x += __shfl_xor(a.x, m);
                a.y += __shfl_xor(a.y, m);
                a.z += __shfl_xor(a.z, m);
                a.w += __shfl_xor(a.w, m);
            }
            float4 lat;
            lat.x = a.x + be4.x; lat.x = lat.x > 0.f ? lat.x : NEG * lat.x;
            lat.y = a.y + be4.y; lat.y = lat.y > 0.f ? lat.y : NEG * lat.y;
            lat.z = a.z + be4.z; lat.z = lat.z > 0.f ? lat.z : NEG * lat.z;
            lat.w = a.w + be4.w; lat.w = lat.w > 0.f ? lat.w : NEG * lat.w;

            float part = lat.x * wa.x + lat.y * wa.y + lat.z * wa.z + lat.w * wa.w;
#pragma unroll
            for (int m = 1; m <= 8; m <<= 1) part += __shfl_xor(part, m);

            float att = 1.f / (1.f + expf(-(part + ba)));
            att *= (j < nb) ? 1.f : 0.f;             // mask clamp-padded edges
            oacc.x += att * lat.x;
            oacc.y += att * lat.y;
            oacc.z += att * lat.z;
            oacc.w += att * lat.w;
        }
    }

    if (fg == 0) *(float4*)&red[w][og * 4] = oacc;
    __syncthreads();

    // write this sub-block's 64-float partial into workspace
    if (t < On) {
        float s = 0.f;
#pragma unroll
        for (int q = 0; q < NW; ++q) s += red[q][t];
        ws[((size_t)bucket * SUBn + sub) * On + t] = s;
    }
}

// ---------------------------------------------------------------------------
// deterministic cross-sub reduction: out[bucket][o] = sum_sub ws[bucket][sub][o]
__global__ void __launch_bounds__(256)
reduce_kernel(const float* __restrict__ ws, float* __restrict__ out) {
    const int i = blockIdx.x * 256 + threadIdx.x;   // 0 .. Bn*Kn*On-1
    const int bucket = i >> 6;
    const int o      = i & (On - 1);
    const float* p = ws + (size_t)bucket * SUBn * On + o;
    float s01 = p[0]      + p[On];
    float s23 = p[2 * On] + p[3 * On];
    float s45 = p[4 * On] + p[5 * On];
    float s67 = p[6 * On] + p[7 * On];
    out[i] = (s01 + s23) + (s45 + s67);
}

// ---------------------------------------------------------------------------
extern "C" void kernel_launch(void* const* d_in, const int* in_sizes, int n_in,
                              void* d_out, int out_size, void* d_ws, size_t ws_size,
                              hipStream_t stream) {
    const float* sites1 = (const float*)d_in[0];
    const float* sites2 = (const float*)d_in[1];
    const float* bonds  = (const float*)d_in[2];
    const float* W_eq   = (const float*)d_in[3];
    const float* b_eq   = (const float*)d_in[4];
    const float* W_att  = (const float*)d_in[5];
    const float* b_att  = (const float*)d_in[6];
    /* d_in[7] = idx2_oh (unused — reduced algebraically) */
    const int*   idx1   = (const int*)d_in[8];
    const int*   idx2   = (const int*)d_in[9];
    const int*   perms1 = (const int*)d_in[10];
    const int*   perms2 = (const int*)d_in[11];
    float* out = (float*)d_out;
    float* ws  = (float*)d_ws;

    fused_kernel<<<Bn * Kn * SUBn, NT, 0, stream>>>(
        sites1, sites2, bonds, W_eq, b_eq, W_att, b_att,
        idx1, idx2, perms1, perms2, ws);
    reduce_kernel<<<(Bn * Kn * On) / 256, 256, 0, stream>>>(ws, out);
}